// Round 6
// baseline (485.195 us; speedup 1.0000x reference)
//
#include <hip/hip_runtime.h>
#include <math.h>
#include <stdint.h>

#define HH 4096
#define WW 4096
#define MAXP 8192
#define ALPHA_F 0.9998f
#define ROWCAP 64   // max peaks recorded per row (Poisson(0.82) => P(>64) ~ 1e-80)

// output layout (floats): probs_valid[0..40959], topk_scores[40960..40975],
// cue_dir[40976..40979], sel_peaks[40980..41011]

// ---------------- helpers ----------------
__device__ __forceinline__ float clampA(float v) {
    float t = fminf(fmaxf(v, 0.f), 1.f);
    return (t < ALPHA_F) ? 0.f : t;
}

__device__ __forceinline__ unsigned long long shflx_u64(unsigned long long v, int m) {
    int lo = __shfl_xor((int)(v & 0xFFFFFFFFull), m);
    int hi = __shfl_xor((int)(v >> 32), m);
    return ((unsigned long long)(unsigned int)hi << 32) | (unsigned int)lo;
}

// ---------------- K1: peak detect (float4) -> per-row x-lists ----------------
// one wave (64 lanes) per row, 4 floats/lane/chunk; 4 rows per block; 1024 blocks
__global__ __launch_bounds__(256) void k_peak(const float* __restrict__ hm,
                                              unsigned short* __restrict__ xlist,
                                              int* __restrict__ rowcount) {
    int row  = blockIdx.x * 4 + (threadIdx.x >> 6);
    int lane = threadIdx.x & 63;
    const float* r = hm + (size_t)row * WW;
    const float4* r4 = (const float4*)r;
    unsigned short* xl = xlist + (size_t)row * ROWCAP;
    int cnt = 0;                         // wave-uniform running count
    for (int ch = 0; ch < 16; ++ch) {
        int v4i = ch * 64 + lane;        // float4 index within the row
        float4 v = r4[v4i];
        float c0 = clampA(v.x), c1 = clampA(v.y), c2 = clampA(v.z), c3 = clampA(v.w);
        bool any4 = (c0 > 0.f) || (c1 > 0.f) || (c2 > 0.f) || (c3 > 0.f);
        unsigned long long bb = __ballot(any4);
        if (bb == 0ull) continue;        // common path: no candidate in 256 pixels
        int pmask = 0;
        if (any4) {
            int x0 = v4i * 4;
            float lft = (x0 > 0)       ? clampA(r[x0 - 1]) : 0.f;
            float rgt = (x0 + 4 < WW)  ? clampA(r[x0 + 4]) : 0.f;
            float cc[4] = {c0, c1, c2, c3};
            float lv[4] = {lft, c0, c1, c2};
            float rv[4] = {c1, c2, c3, rgt};
            #pragma unroll
            for (int e = 0; e < 4; ++e) {
                if (cc[e] > 0.f && cc[e] > lv[e] && cc[e] > rv[e]) {
                    int x = x0 + e;
                    float up = (row > 0)      ? clampA(hm[(size_t)(row - 1) * WW + x]) : 0.f;
                    float dn = (row < HH - 1) ? clampA(hm[(size_t)(row + 1) * WW + x]) : 0.f;
                    if (cc[e] > up && cc[e] > dn) pmask |= (1 << e);
                }
            }
        }
        int pc = __popc(pmask);
        int incl = pc;                   // wave prefix scan (lane order == x order)
        #pragma unroll
        for (int d = 1; d < 64; d <<= 1) {
            int o = __shfl_up(incl, d);
            if (lane >= d) incl += o;
        }
        int pos = cnt + incl - pc;
        while (pmask) {
            int e = __builtin_ctz(pmask);
            if (pos < ROWCAP) xl[pos] = (unsigned short)(v4i * 4 + e);
            ++pos;
            pmask &= pmask - 1;
        }
        cnt += __shfl(incl, 63);         // wave total, uniform
    }
    if (lane == 0) rowcount[row] = min(cnt, ROWCAP);
}

// ---------------- K2: scan row counts + emit coords + inits (single block) -------
__global__ __launch_bounds__(1024) void k_scan(const int* __restrict__ rowcount,
                                               const unsigned short* __restrict__ xlist,
                                               int* __restrict__ Pp,
                                               int* __restrict__ cy, int* __restrict__ cx) {
    __shared__ int sums[1024];
    int tid = threadIdx.x;
    int base = tid * 4;
    int a0 = rowcount[base + 0];
    int a1 = rowcount[base + 1];
    int a2 = rowcount[base + 2];
    int a3 = rowcount[base + 3];
    int s = a0 + a1 + a2 + a3;
    sums[tid] = s;
    __syncthreads();
    for (int d = 1; d < 1024; d <<= 1) {   // Hillis-Steele inclusive scan
        int v = (tid >= d) ? sums[tid - d] : 0;
        __syncthreads();
        if (tid >= d) sums[tid] += v;
        __syncthreads();
    }
    int excl = sums[tid] - s;
    int total = sums[1023];
    int P = min(total, MAXP);
    // emit this thread's 4 rows (row-major global order == jnp.nonzero order)
    int cnts[4] = {a0, a1, a2, a3};
    int pos = excl;
    #pragma unroll
    for (int r = 0; r < 4; ++r) {
        int row = base + r;
        const unsigned short* xl = xlist + (size_t)row * ROWCAP;
        for (int t = 0; t < cnts[r]; ++t) {
            if (pos < MAXP) { cy[pos] = row; cx[pos] = (int)xl[t]; }
            ++pos;
        }
    }
    // fill tail with -1 (jnp.nonzero fill_value)
    for (int i = P + tid; i < MAXP; i += 1024) { cy[i] = -1; cx[i] = -1; }
    if (tid == 0) *Pp = P;
}

// ---------------- K3: fused NMS + batched window gather + logits + softmax -------
// block b handles peaks [8b, 8b+8): recomputes NMS for them, then label_W row
// loaded once and applied to up to 8 windows. Emits per-class u32 keys.
__global__ __launch_bounds__(256) void k_logits(const float* __restrict__ img,
                                                const float* __restrict__ lW,
                                                const float* __restrict__ lb,
                                                const int* __restrict__ cy,
                                                const int* __restrict__ cx,
                                                const int* __restrict__ Pp,
                                                float* __restrict__ outP,
                                                unsigned int* __restrict__ clskeys) {
    int tid = threadIdx.x;
    int i0 = blockIdx.x * 8;
    int P = *Pp;

    if (i0 >= P) {                       // whole block out of range: zero & exit
        if (tid < 8) {
            int i = i0 + tid;
            #pragma unroll
            for (int o = 0; o < 5; ++o) outP[(size_t)i * 5 + o] = 0.f;
            #pragma unroll
            for (int o = 0; o < 5; ++o) clskeys[o * MAXP + i] = 0u;
        }
        return;
    }

    bool inP[8];
    int ys[8], xs[8];
    #pragma unroll
    for (int p = 0; p < 8; ++p) {
        int i = i0 + p;
        inP[p] = (i < P);
        ys[p] = cy[i]; xs[p] = cx[i];
    }

    // ---- NMS for these 8 peaks (XLA f32 arithmetic exactly) ----
    __shared__ int rejMaskS;
    if (tid == 0) rejMaskS = 0;
    __syncthreads();
    float n2i[8];
    #pragma unroll
    for (int p = 0; p < 8; ++p)
        n2i[p] = (float)(ys[p] * ys[p] + xs[p] * xs[p]);   // single rounding == XLA
    int rbits = 0;
    for (int j = tid; j < P; j += 256) {
        int yj = cy[j], xj = cx[j];
        float n2j = (float)(yj * yj + xj * xj);
        #pragma unroll
        for (int p = 0; p < 8; ++p) {
            float dot = (float)(ys[p] * yj + xs[p] * xj);  // exact int, one rounding == XLA
            float d2 = (n2i[p] + n2j) - 2.0f * dot;        // == n2[:,None]+n2[None,:]-2*(cf@cf.T)
            if ((d2 > 1.0f) && (d2 < 25.0f)) rbits |= (1 << p);
        }
    }
    if (rbits) atomicOr(&rejMaskS, rbits);                 // LDS atomic, order-free
    __syncthreads();
    int rejMask = rejMaskS;

    bool kp[8];                          // static-indexed only (rule #20)
    bool anyk = false;
    #pragma unroll
    for (int p = 0; p < 8; ++p) {
        kp[p] = inP[p] && !((rejMask >> p) & 1);
        anyk |= kp[p];
    }
    // zero outputs of non-kept rows
    if (tid < 8) {
        int i = i0 + tid;
        bool k2 = (i < P) && !((rejMask >> tid) & 1);
        if (!k2) {
            #pragma unroll
            for (int o = 0; o < 5; ++o) outP[(size_t)i * 5 + o] = 0.f;
            #pragma unroll
            for (int o = 0; o < 5; ++o) clskeys[o * MAXP + i] = 0u;
        }
    }
    if (!anyk) return;

    // ---- window gather + GEMV ----
    float acc[8][5];
    #pragma unroll
    for (int p = 0; p < 8; ++p)
        #pragma unroll
        for (int o = 0; o < 5; ++o) acc[p][o] = 0.f;

    for (int m = 0; m < 12; ++m) {
        int k  = tid + m * 256;          // feature index: c*1024 + wy*32 + wx
        int c  = k >> 10;
        int r  = (k >> 5) & 31;
        int wx = k & 31;
        const float* wr = lW + (size_t)k * 5;
        float w0 = wr[0], w1 = wr[1], w2 = wr[2], w3 = wr[3], w4 = wr[4];
        #pragma unroll
        for (int p = 0; p < 8; ++p) {
            if (!kp[p]) continue;        // uniform across block
            int iy = ys[p] - 16 + r, ix = xs[p] - 16 + wx;
            float f = 0.f;
            if ((unsigned)iy < 4096u && (unsigned)ix < 4096u)
                f = img[(size_t)c * 16777216u + (size_t)iy * 4096u + (unsigned)ix];
            acc[p][0] += f * w0;
            acc[p][1] += f * w1;
            acc[p][2] += f * w2;
            acc[p][3] += f * w3;
            acc[p][4] += f * w4;
        }
    }
    // wave shuffle reduce, then cross-wave via LDS
    __shared__ float wsum[4][8][5];
    int wid = tid >> 6, lane = tid & 63;
    #pragma unroll
    for (int p = 0; p < 8; ++p) {
        #pragma unroll
        for (int off = 32; off > 0; off >>= 1) {
            #pragma unroll
            for (int o = 0; o < 5; ++o) acc[p][o] += __shfl_xor(acc[p][o], off);
        }
        if (lane == 0) {
            #pragma unroll
            for (int o = 0; o < 5; ++o) wsum[wid][p][o] = acc[p][o];
        }
    }
    __syncthreads();
    // per-peak softmax: threads 0..7, one peak each
    if (tid < 8) {
        int i = i0 + tid;
        bool k2 = (i < P) && !((rejMask >> tid) & 1);
        if (k2) {
            float z[5], sh[5], pr[5];
            #pragma unroll
            for (int o = 0; o < 5; ++o)
                z[o] = wsum[0][tid][o] + wsum[1][tid][o] + wsum[2][tid][o] + wsum[3][tid][o] + lb[o];
            float mx = z[0];
            #pragma unroll
            for (int o = 1; o < 5; ++o) mx = fmaxf(mx, z[o]);
            float s = 0.f;
            #pragma unroll
            for (int o = 0; o < 5; ++o) { sh[o] = z[o] - mx; s += expf(sh[o]); }
            float ls = logf(s);
            float best = -1.f; int bi = 0;
            #pragma unroll
            for (int o = 0; o < 5; ++o) {
                pr[o] = expf(sh[o] - ls);            // exp(log_softmax) as in reference
                if (pr[o] > best) { best = pr[o]; bi = o; }
            }
            int v = (best > 0.3f) ? 1 : 0;
            #pragma unroll
            for (int o = 0; o < 5; ++o) outP[(size_t)i * 5 + o] = v ? pr[o] : 0.f;
            unsigned int sb = __float_as_uint(best);
            #pragma unroll
            for (int o = 0; o < 5; ++o)
                clskeys[o * MAXP + i] = (v && bi == o) ? sb : 0u;
        }
    }
}

// ---------------- K4: wave-parallel per-class top-k + cue-dir head ----------------
// wave 0: class 0 (k=1) then class 4 (k=2); wave 1: class 1 (k=1);
// wave 2: class 2 (k=6); wave 3: class 3 (k=6). No barriers during selection.
__global__ __launch_bounds__(256) void k_topk(const unsigned int* __restrict__ clskeys,
                                              const int* __restrict__ cy,
                                              const int* __restrict__ cx,
                                              const float* __restrict__ img,
                                              const float* __restrict__ dW,
                                              const float* __restrict__ db,
                                              float* __restrict__ out) {
    int tid = threadIdx.x;
    int wid = tid >> 6, lane = tid & 63;
    __shared__ int cueS[2];
    const int baseOf[5] = {0, 1, 2, 8, 14};   // outPos base per class (k=1,1,6,6,2)
    for (int a = 0; a < 2; ++a) {
        int c, kk;
        if (a == 0) { c = wid; kk = (wid < 2) ? 1 : 6; }
        else { if (wid != 0) break; c = 4; kk = 2; }
        const unsigned int* hiArr = clskeys + (size_t)c * MAXP;
        unsigned long long prevKey = ~0ull;
        int base = baseOf[c];
        for (int t = 0; t < kk; ++t) {
            // key = (score_bits_if_class_c << 32) | (~i); strictly ordered, distinct.
            // hi==0 entries keep (~i) => stable ascending-index picks for the -inf
            // pool, matching jax.lax.top_k.
            unsigned long long best = 0;
            for (int i = lane; i < MAXP; i += 64) {
                unsigned long long key = ((unsigned long long)hiArr[i] << 32)
                                       | (0xFFFFFFFFu - (unsigned int)i);
                if (key >= prevKey) key = 0;   // exclude earlier picks of this class
                if (key > best) best = key;
            }
            #pragma unroll
            for (int off = 32; off > 0; off >>= 1) {
                unsigned long long o = shflx_u64(best, off);
                if (o > best) best = o;
            }
            prevKey = best;                    // butterfly => uniform across wave
            int win = (int)(0xFFFFFFFFu - (unsigned int)(best & 0xFFFFFFFFull));
            if (lane == 0) {
                unsigned int hi = (unsigned int)(best >> 32);
                int pos = base + t;
                out[40960 + pos] = hi ? __uint_as_float(hi) : 0.f;  // isfinite ? v : 0
                out[40980 + pos * 2 + 0] = (float)cy[win];          // sel_peaks
                out[40980 + pos * 2 + 1] = (float)cx[win];
                if (c == 4) cueS[t] = win;
            }
        }
    }
    __syncthreads();
    // ---- cue-dir head: feats[cue_idx] @ dir_W + dir_b, rows flipped ----
    #pragma unroll
    for (int s = 0; s < 2; ++s) {
        int i = cueS[s];
        int y = max(cy[i], 0), x = max(cx[i], 0);   // starts = clip(coords, 0)
        float a0 = 0.f, a1 = 0.f;
        for (int m = 0; m < 12; ++m) {
            int k  = tid + m * 256;
            int c  = k >> 10;
            int r  = (k >> 5) & 31;
            int wx = k & 31;
            int iy = y - 16 + r, ix = x - 16 + wx;
            float f = 0.f;
            if ((unsigned)iy < 4096u && (unsigned)ix < 4096u)
                f = img[(size_t)c * 16777216u + (size_t)iy * 4096u + (unsigned)ix];
            a0 += f * dW[(size_t)k * 2 + 0];
            a1 += f * dW[(size_t)k * 2 + 1];
        }
        #pragma unroll
        for (int off = 32; off > 0; off >>= 1) {
            a0 += __shfl_xor(a0, off);
            a1 += __shfl_xor(a1, off);
        }
        __shared__ float wa[4][2];
        if (lane == 0) { wa[wid][0] = a0; wa[wid][1] = a1; }
        __syncthreads();
        if (tid == 0) {
            float s0 = wa[0][0] + wa[1][0] + wa[2][0] + wa[3][0] + db[0];
            float s1 = wa[0][1] + wa[1][1] + wa[2][1] + wa[3][1] + db[1];
            // cue_dir = flip(rows): pick s writes output row (1-s)
            out[40976 + (1 - s) * 2 + 0] = s0;
            out[40976 + (1 - s) * 2 + 1] = s1;
        }
        __syncthreads();
    }
}

// ---------------- launch ----------------
extern "C" void kernel_launch(void* const* d_in, const int* in_sizes, int n_in,
                              void* d_out, int out_size, void* d_ws, size_t ws_size,
                              hipStream_t stream) {
    const float* hm  = (const float*)d_in[0];
    const float* img = (const float*)d_in[1];
    const float* lW  = (const float*)d_in[2];
    const float* lb  = (const float*)d_in[3];
    const float* dW  = (const float*)d_in[4];
    const float* db  = (const float*)d_in[5];
    float* out = (float*)d_out;

    uint8_t* w = (uint8_t*)d_ws;
    unsigned short* xlist  = (unsigned short*)(w + 0);         // 4096*64*2 = 524288 B
    int*          rowcount = (int*)          (w + 524288);     // 16384 B
    int*          cy       = (int*)          (w + 540672);     // 32768 B
    int*          cx       = (int*)          (w + 573440);     // 32768 B
    unsigned int* clskeys  = (unsigned int*) (w + 606208);     // 5*8192*4 = 163840 B
    int*          Pp       = (int*)          (w + 770048);     // 4 B

    hipLaunchKernelGGL(k_peak,   dim3(1024), dim3(256),  0, stream, hm, xlist, rowcount);
    hipLaunchKernelGGL(k_scan,   dim3(1),    dim3(1024), 0, stream, rowcount, xlist, Pp, cy, cx);
    hipLaunchKernelGGL(k_logits, dim3(1024), dim3(256),  0, stream, img, lW, lb, cy, cx, Pp,
                       out, clskeys);
    hipLaunchKernelGGL(k_topk,   dim3(1),    dim3(256),  0, stream, clskeys, cy, cx,
                       img, dW, db, out);
}

// Round 7
// 376.174 us; speedup vs baseline: 1.2898x; 1.2898x over previous
//
#include <hip/hip_runtime.h>
#include <math.h>
#include <stdint.h>

#define HH 4096
#define WW 4096
#define MAXP 8192
#define ALPHA_F 0.9998f
#define ROWCAP 64   // max peaks recorded per row (Poisson(0.82) => P(>64) ~ 1e-80)

// output layout (floats): probs_valid[0..40959], topk_scores[40960..40975],
// cue_dir[40976..40979], sel_peaks[40980..41011]

// ---------------- helpers ----------------
__device__ __forceinline__ float clampA(float v) {
    float t = fminf(fmaxf(v, 0.f), 1.f);
    return (t < ALPHA_F) ? 0.f : t;
}

__device__ __forceinline__ unsigned long long shflx_u64(unsigned long long v, int m) {
    int lo = __shfl_xor((int)(v & 0xFFFFFFFFull), m);
    int hi = __shfl_xor((int)(v >> 32), m);
    return ((unsigned long long)(unsigned int)hi << 32) | (unsigned int)lo;
}

// ---------------- K1: peak detect (float4) -> per-row x-lists ----------------
// one wave (64 lanes) per row, 4 floats/lane/chunk; 4 rows per block; 1024 blocks
__global__ __launch_bounds__(256) void k_peak(const float* __restrict__ hm,
                                              unsigned short* __restrict__ xlist,
                                              int* __restrict__ rowcount) {
    int row  = blockIdx.x * 4 + (threadIdx.x >> 6);
    int lane = threadIdx.x & 63;
    const float* r = hm + (size_t)row * WW;
    const float4* r4 = (const float4*)r;
    unsigned short* xl = xlist + (size_t)row * ROWCAP;
    int cnt = 0;                         // wave-uniform running count
    for (int ch = 0; ch < 16; ++ch) {
        int v4i = ch * 64 + lane;        // float4 index within the row
        float4 v = r4[v4i];
        float c0 = clampA(v.x), c1 = clampA(v.y), c2 = clampA(v.z), c3 = clampA(v.w);
        bool any4 = (c0 > 0.f) || (c1 > 0.f) || (c2 > 0.f) || (c3 > 0.f);
        unsigned long long bb = __ballot(any4);
        if (bb == 0ull) continue;        // common path: no candidate in 256 pixels
        int pmask = 0;
        if (any4) {
            int x0 = v4i * 4;
            float lft = (x0 > 0)       ? clampA(r[x0 - 1]) : 0.f;
            float rgt = (x0 + 4 < WW)  ? clampA(r[x0 + 4]) : 0.f;
            float cc[4] = {c0, c1, c2, c3};
            float lv[4] = {lft, c0, c1, c2};
            float rv[4] = {c1, c2, c3, rgt};
            #pragma unroll
            for (int e = 0; e < 4; ++e) {
                if (cc[e] > 0.f && cc[e] > lv[e] && cc[e] > rv[e]) {
                    int x = x0 + e;
                    float up = (row > 0)      ? clampA(hm[(size_t)(row - 1) * WW + x]) : 0.f;
                    float dn = (row < HH - 1) ? clampA(hm[(size_t)(row + 1) * WW + x]) : 0.f;
                    if (cc[e] > up && cc[e] > dn) pmask |= (1 << e);
                }
            }
        }
        int pc = __popc(pmask);
        int incl = pc;                   // wave prefix scan (lane order == x order)
        #pragma unroll
        for (int d = 1; d < 64; d <<= 1) {
            int o = __shfl_up(incl, d);
            if (lane >= d) incl += o;
        }
        int pos = cnt + incl - pc;
        while (pmask) {
            int e = __builtin_ctz(pmask);
            if (pos < ROWCAP) xl[pos] = (unsigned short)(v4i * 4 + e);
            ++pos;
            pmask &= pmask - 1;
        }
        cnt += __shfl(incl, 63);         // wave total, uniform
    }
    if (lane == 0) rowcount[row] = min(cnt, ROWCAP);
}

// ---------------- K2: scan row counts + emit coords + inits (single block) -------
__global__ __launch_bounds__(1024) void k_scan(const int* __restrict__ rowcount,
                                               const unsigned short* __restrict__ xlist,
                                               int* __restrict__ Pp,
                                               int* __restrict__ cy, int* __restrict__ cx) {
    __shared__ int sums[1024];
    int tid = threadIdx.x;
    int base = tid * 4;
    int a0 = rowcount[base + 0];
    int a1 = rowcount[base + 1];
    int a2 = rowcount[base + 2];
    int a3 = rowcount[base + 3];
    int s = a0 + a1 + a2 + a3;
    sums[tid] = s;
    __syncthreads();
    for (int d = 1; d < 1024; d <<= 1) {   // Hillis-Steele inclusive scan
        int v = (tid >= d) ? sums[tid - d] : 0;
        __syncthreads();
        if (tid >= d) sums[tid] += v;
        __syncthreads();
    }
    int excl = sums[tid] - s;
    int total = sums[1023];
    int P = min(total, MAXP);
    // emit this thread's 4 rows (row-major global order == jnp.nonzero order)
    int cnts[4] = {a0, a1, a2, a3};
    int pos = excl;
    #pragma unroll
    for (int r = 0; r < 4; ++r) {
        int row = base + r;
        const unsigned short* xl = xlist + (size_t)row * ROWCAP;
        for (int t = 0; t < cnts[r]; ++t) {
            if (pos < MAXP) { cy[pos] = row; cx[pos] = (int)xl[t]; }
            ++pos;
        }
    }
    // fill tail with -1 (jnp.nonzero fill_value)
    for (int i = P + tid; i < MAXP; i += 1024) { cy[i] = -1; cx[i] = -1; }
    if (tid == 0) *Pp = P;
}

// ---------------- K3: fused NMS + batched window gather + logits + softmax -------
// block b handles peaks [8b, 8b+8): recomputes NMS for them, then label_W row
// loaded once and applied to up to 8 windows. Emits per-class u32 keys.
__global__ __launch_bounds__(256) void k_logits(const float* __restrict__ img,
                                                const float* __restrict__ lW,
                                                const float* __restrict__ lb,
                                                const int* __restrict__ cy,
                                                const int* __restrict__ cx,
                                                const int* __restrict__ Pp,
                                                float* __restrict__ outP,
                                                unsigned int* __restrict__ clskeys) {
    int tid = threadIdx.x;
    int i0 = blockIdx.x * 8;
    int P = *Pp;

    if (i0 >= P) {                       // whole block out of range: zero & exit
        if (tid < 8) {
            int i = i0 + tid;
            #pragma unroll
            for (int o = 0; o < 5; ++o) outP[(size_t)i * 5 + o] = 0.f;
            #pragma unroll
            for (int o = 0; o < 5; ++o) clskeys[o * MAXP + i] = 0u;
        }
        return;
    }

    bool inP[8];
    int ys[8], xs[8];
    #pragma unroll
    for (int p = 0; p < 8; ++p) {
        int i = i0 + p;
        inP[p] = (i < P);
        ys[p] = cy[i]; xs[p] = cx[i];
    }

    // ---- NMS for these 8 peaks (XLA f32 arithmetic exactly) ----
    __shared__ int rejMaskS;
    if (tid == 0) rejMaskS = 0;
    __syncthreads();
    float n2i[8];
    #pragma unroll
    for (int p = 0; p < 8; ++p)
        n2i[p] = (float)(ys[p] * ys[p] + xs[p] * xs[p]);   // single rounding == XLA
    int rbits = 0;
    for (int j = tid; j < P; j += 256) {
        int yj = cy[j], xj = cx[j];
        float n2j = (float)(yj * yj + xj * xj);
        #pragma unroll
        for (int p = 0; p < 8; ++p) {
            float dot = (float)(ys[p] * yj + xs[p] * xj);  // exact int, one rounding == XLA
            float d2 = (n2i[p] + n2j) - 2.0f * dot;        // == n2[:,None]+n2[None,:]-2*(cf@cf.T)
            if ((d2 > 1.0f) && (d2 < 25.0f)) rbits |= (1 << p);
        }
    }
    if (rbits) atomicOr(&rejMaskS, rbits);                 // LDS atomic, order-free
    __syncthreads();
    int rejMask = rejMaskS;

    bool kp[8];                          // static-indexed only (rule #20)
    bool anyk = false;
    #pragma unroll
    for (int p = 0; p < 8; ++p) {
        kp[p] = inP[p] && !((rejMask >> p) & 1);
        anyk |= kp[p];
    }
    // zero outputs of non-kept rows
    if (tid < 8) {
        int i = i0 + tid;
        bool k2 = (i < P) && !((rejMask >> tid) & 1);
        if (!k2) {
            #pragma unroll
            for (int o = 0; o < 5; ++o) outP[(size_t)i * 5 + o] = 0.f;
            #pragma unroll
            for (int o = 0; o < 5; ++o) clskeys[o * MAXP + i] = 0u;
        }
    }
    if (!anyk) return;

    // ---- window gather + GEMV ----
    float acc[8][5];
    #pragma unroll
    for (int p = 0; p < 8; ++p)
        #pragma unroll
        for (int o = 0; o < 5; ++o) acc[p][o] = 0.f;

    for (int m = 0; m < 12; ++m) {
        int k  = tid + m * 256;          // feature index: c*1024 + wy*32 + wx
        int c  = k >> 10;
        int r  = (k >> 5) & 31;
        int wx = k & 31;
        const float* wr = lW + (size_t)k * 5;
        float w0 = wr[0], w1 = wr[1], w2 = wr[2], w3 = wr[3], w4 = wr[4];
        #pragma unroll
        for (int p = 0; p < 8; ++p) {
            if (!kp[p]) continue;        // uniform across block
            int iy = ys[p] - 16 + r, ix = xs[p] - 16 + wx;
            float f = 0.f;
            if ((unsigned)iy < 4096u && (unsigned)ix < 4096u)
                f = img[(size_t)c * 16777216u + (size_t)iy * 4096u + (unsigned)ix];
            acc[p][0] += f * w0;
            acc[p][1] += f * w1;
            acc[p][2] += f * w2;
            acc[p][3] += f * w3;
            acc[p][4] += f * w4;
        }
    }
    // wave shuffle reduce, then cross-wave via LDS
    __shared__ float wsum[4][8][5];
    int wid = tid >> 6, lane = tid & 63;
    #pragma unroll
    for (int p = 0; p < 8; ++p) {
        #pragma unroll
        for (int off = 32; off > 0; off >>= 1) {
            #pragma unroll
            for (int o = 0; o < 5; ++o) acc[p][o] += __shfl_xor(acc[p][o], off);
        }
        if (lane == 0) {
            #pragma unroll
            for (int o = 0; o < 5; ++o) wsum[wid][p][o] = acc[p][o];
        }
    }
    __syncthreads();
    // per-peak softmax: threads 0..7, one peak each
    if (tid < 8) {
        int i = i0 + tid;
        bool k2 = (i < P) && !((rejMask >> tid) & 1);
        if (k2) {
            float z[5], sh[5], pr[5];
            #pragma unroll
            for (int o = 0; o < 5; ++o)
                z[o] = wsum[0][tid][o] + wsum[1][tid][o] + wsum[2][tid][o] + wsum[3][tid][o] + lb[o];
            float mx = z[0];
            #pragma unroll
            for (int o = 1; o < 5; ++o) mx = fmaxf(mx, z[o]);
            float s = 0.f;
            #pragma unroll
            for (int o = 0; o < 5; ++o) { sh[o] = z[o] - mx; s += expf(sh[o]); }
            float ls = logf(s);
            float best = -1.f; int bi = 0;
            #pragma unroll
            for (int o = 0; o < 5; ++o) {
                pr[o] = expf(sh[o] - ls);            // exp(log_softmax) as in reference
                if (pr[o] > best) { best = pr[o]; bi = o; }
            }
            int v = (best > 0.3f) ? 1 : 0;
            #pragma unroll
            for (int o = 0; o < 5; ++o) outP[(size_t)i * 5 + o] = v ? pr[o] : 0.f;
            unsigned int sb = __float_as_uint(best);
            #pragma unroll
            for (int o = 0; o < 5; ++o)
                clskeys[o * MAXP + i] = (v && bi == o) ? sb : 0u;
        }
    }
}

// ---------------- K4: single-pass wave top-k + cue-dir head ----------------
// Per-lane sorted top-6 list built in ONE uint4-vectorized pass (keys embed ~i
// so scan order is irrelevant), then kk tournament rounds (butterfly max +
// owner-shift). No barriers during selection, no rescans.
#define INS6(KEY) do { unsigned long long v_ = (KEY); \
    if (v_ > l0) { unsigned long long t_ = l0; l0 = v_; v_ = t_; } \
    if (v_ > l1) { unsigned long long t_ = l1; l1 = v_; v_ = t_; } \
    if (v_ > l2) { unsigned long long t_ = l2; l2 = v_; v_ = t_; } \
    if (v_ > l3) { unsigned long long t_ = l3; l3 = v_; v_ = t_; } \
    if (v_ > l4) { unsigned long long t_ = l4; l4 = v_; v_ = t_; } \
    if (v_ > l5) { l5 = v_; } } while (0)

__device__ __forceinline__ void wave_topk(const unsigned int* __restrict__ hiArr,
                                          int PM, int kk, int base,
                                          const int* __restrict__ cy,
                                          const int* __restrict__ cx,
                                          float* __restrict__ out,
                                          int* cueS, bool isCue, int lane) {
    unsigned long long l0 = 0, l1 = 0, l2 = 0, l3 = 0, l4 = 0, l5 = 0;
    for (int g = 0; g < PM; g += 256) {
        int idx = g + lane * 4;
        uint4 kv = *(const uint4*)(hiArr + idx);
        // key = (score_bits << 32) | (~i): descending score, ascending index on
        // ties / -inf pool -> exactly jax.lax.top_k's stable order.
        unsigned long long k0 = ((unsigned long long)kv.x << 32) | (0xFFFFFFFFu - (unsigned)(idx + 0));
        unsigned long long k1 = ((unsigned long long)kv.y << 32) | (0xFFFFFFFFu - (unsigned)(idx + 1));
        unsigned long long k2 = ((unsigned long long)kv.z << 32) | (0xFFFFFFFFu - (unsigned)(idx + 2));
        unsigned long long k3 = ((unsigned long long)kv.w << 32) | (0xFFFFFFFFu - (unsigned)(idx + 3));
        INS6(k0); INS6(k1); INS6(k2); INS6(k3);
    }
    for (int t = 0; t < kk; ++t) {
        unsigned long long w = l0;
        #pragma unroll
        for (int off = 32; off > 0; off >>= 1) {
            unsigned long long o = shflx_u64(w, off);
            if (o > w) w = o;
        }
        if (l0 == w) { l0 = l1; l1 = l2; l2 = l3; l3 = l4; l4 = l5; l5 = 0; }  // unique owner
        int win = (int)(0xFFFFFFFFu - (unsigned int)(w & 0xFFFFFFFFull));
        if (lane == 0) {
            unsigned int hi = (unsigned int)(w >> 32);
            int pos = base + t;
            out[40960 + pos] = hi ? __uint_as_float(hi) : 0.f;  // isfinite ? v : 0
            out[40980 + pos * 2 + 0] = (float)cy[win];          // sel_peaks
            out[40980 + pos * 2 + 1] = (float)cx[win];
            if (isCue) cueS[t] = win;
        }
    }
}

__global__ __launch_bounds__(256) void k_topk(const unsigned int* __restrict__ clskeys,
                                              const int* __restrict__ cy,
                                              const int* __restrict__ cx,
                                              const int* __restrict__ Pp,
                                              const float* __restrict__ img,
                                              const float* __restrict__ dW,
                                              const float* __restrict__ db,
                                              float* __restrict__ out) {
    int tid = threadIdx.x;
    int wid = tid >> 6, lane = tid & 63;
    __shared__ int cueS[2];
    int P = *Pp;
    int PM = min(MAXP, ((max(P, 16) + 255) / 256) * 256);  // truncation exact for P>=16
    // classes (k): 0(1) 1(1) 2(6) 3(6) 4(2); outPos bases: 0,1,2,8,14
    if (wid == 0) {
        wave_topk(clskeys + 0 * MAXP, PM, 1, 0,  cy, cx, out, cueS, false, lane);
        wave_topk(clskeys + 4 * MAXP, PM, 2, 14, cy, cx, out, cueS, true,  lane);
    } else if (wid == 1) {
        wave_topk(clskeys + 1 * MAXP, PM, 1, 1,  cy, cx, out, cueS, false, lane);
    } else if (wid == 2) {
        wave_topk(clskeys + 2 * MAXP, PM, 6, 2,  cy, cx, out, cueS, false, lane);
    } else {
        wave_topk(clskeys + 3 * MAXP, PM, 6, 8,  cy, cx, out, cueS, false, lane);
    }
    __syncthreads();
    // ---- cue-dir head: both class-4 windows gathered in one fused pass ----
    int ia = cueS[0], ib = cueS[1];
    int ya = max(cy[ia], 0), xa = max(cx[ia], 0);   // starts = clip(coords, 0)
    int yb = max(cy[ib], 0), xb = max(cx[ib], 0);
    float a00 = 0.f, a01 = 0.f, a10 = 0.f, a11 = 0.f;
    #pragma unroll
    for (int m = 0; m < 12; ++m) {
        int k  = tid + m * 256;
        int c  = k >> 10;
        int r  = (k >> 5) & 31;
        int wx = k & 31;
        float w0 = dW[(size_t)k * 2 + 0];
        float w1 = dW[(size_t)k * 2 + 1];
        int iya = ya - 16 + r, ixa = xa - 16 + wx;
        int iyb = yb - 16 + r, ixb = xb - 16 + wx;
        float fa = 0.f, fb = 0.f;
        if ((unsigned)iya < 4096u && (unsigned)ixa < 4096u)
            fa = img[(size_t)c * 16777216u + (size_t)iya * 4096u + (unsigned)ixa];
        if ((unsigned)iyb < 4096u && (unsigned)ixb < 4096u)
            fb = img[(size_t)c * 16777216u + (size_t)iyb * 4096u + (unsigned)ixb];
        a00 += fa * w0;   // pick 0: same per-pick FP order as before
        a01 += fa * w1;
        a10 += fb * w0;
        a11 += fb * w1;
    }
    #pragma unroll
    for (int off = 32; off > 0; off >>= 1) {
        a00 += __shfl_xor(a00, off);
        a01 += __shfl_xor(a01, off);
        a10 += __shfl_xor(a10, off);
        a11 += __shfl_xor(a11, off);
    }
    __shared__ float wa[4][4];
    if (lane == 0) { wa[wid][0] = a00; wa[wid][1] = a01; wa[wid][2] = a10; wa[wid][3] = a11; }
    __syncthreads();
    if (tid == 0) {
        // cue_dir = flip(rows): pick s writes output row (1-s)
        out[40976 + 1 * 2 + 0] = wa[0][0] + wa[1][0] + wa[2][0] + wa[3][0] + db[0];
        out[40976 + 1 * 2 + 1] = wa[0][1] + wa[1][1] + wa[2][1] + wa[3][1] + db[1];
        out[40976 + 0 * 2 + 0] = wa[0][2] + wa[1][2] + wa[2][2] + wa[3][2] + db[0];
        out[40976 + 0 * 2 + 1] = wa[0][3] + wa[1][3] + wa[2][3] + wa[3][3] + db[1];
    }
}

// ---------------- launch ----------------
extern "C" void kernel_launch(void* const* d_in, const int* in_sizes, int n_in,
                              void* d_out, int out_size, void* d_ws, size_t ws_size,
                              hipStream_t stream) {
    const float* hm  = (const float*)d_in[0];
    const float* img = (const float*)d_in[1];
    const float* lW  = (const float*)d_in[2];
    const float* lb  = (const float*)d_in[3];
    const float* dW  = (const float*)d_in[4];
    const float* db  = (const float*)d_in[5];
    float* out = (float*)d_out;

    uint8_t* w = (uint8_t*)d_ws;
    unsigned short* xlist  = (unsigned short*)(w + 0);         // 4096*64*2 = 524288 B
    int*          rowcount = (int*)          (w + 524288);     // 16384 B
    int*          cy       = (int*)          (w + 540672);     // 32768 B
    int*          cx       = (int*)          (w + 573440);     // 32768 B
    unsigned int* clskeys  = (unsigned int*) (w + 606208);     // 5*8192*4 = 163840 B
    int*          Pp       = (int*)          (w + 770048);     // 4 B

    hipLaunchKernelGGL(k_peak,   dim3(1024), dim3(256),  0, stream, hm, xlist, rowcount);
    hipLaunchKernelGGL(k_scan,   dim3(1),    dim3(1024), 0, stream, rowcount, xlist, Pp, cy, cx);
    hipLaunchKernelGGL(k_logits, dim3(1024), dim3(256),  0, stream, img, lW, lb, cy, cx, Pp,
                       out, clskeys);
    hipLaunchKernelGGL(k_topk,   dim3(1),    dim3(256),  0, stream, clskeys, cy, cx, Pp,
                       img, dW, db, out);
}